// Round 2
// baseline (185.102 us; speedup 1.0000x reference)
//
#include <hip/hip_runtime.h>
#include <hip/hip_bf16.h>

typedef __bf16 bf16x8 __attribute__((ext_vector_type(8)));
typedef float  f32x4  __attribute__((ext_vector_type(4)));

static constexpr int S  = 64;    // DIM_S
static constexpr int C  = 8;     // DIM_C (experts)
static constexpr int HD = 256;   // hidden width

__device__ __forceinline__ unsigned short f2bf(float f) {
  __hip_bfloat16 b = __float2bfloat16(f);
  unsigned short u;
  __builtin_memcpy(&u, &b, 2);
  return u;
}

// ws layout: W1T bf16 [C][HD][S]  (131072 elems) at offset 0
//            W2T bf16 [C][HD][HD] (524288 elems) after it
__global__ __launch_bounds__(256) void prep_weights(
    const float* __restrict__ W1, const float* __restrict__ W2,
    unsigned short* __restrict__ W1T, unsigned short* __restrict__ W2T)
{
  int idx = blockIdx.x * 256 + threadIdx.x;   // 0 .. 524287
  // W2T[c][n][k] = bf16(W2[c][k][n])
  {
    int c = idx >> 16;
    int o = idx & 65535;
    int n = o >> 8;
    int k = o & 255;
    W2T[idx] = f2bf(W2[(c << 16) + (k << 8) + n]);
  }
  if (idx < C * HD * S) {
    // W1T[c][h][s] = bf16(W1[c][s][h])
    int c = idx >> 14;
    int o = idx & 16383;
    int h = o >> 6;
    int s = o & 63;
    W1T[idx] = f2bf(W1[(c << 14) + (s << 8) + h]);
  }
}

// One block: 128 batch rows x 1 expert. 256 threads = 4 waves, 32 rows/wave.
__global__ __launch_bounds__(256, 2) void moe_fused(
    const float* __restrict__ st,
    const unsigned short* __restrict__ W1T,
    const unsigned short* __restrict__ W2T,
    const float* __restrict__ b1,
    const float* __restrict__ b2,
    const float* __restrict__ W3,
    const float* __restrict__ b3,
    float* __restrict__ out)
{
  constexpr int LDA  = 72;   // sA row pitch (64 data + 8 pad bf16) -> 2-way banks
  constexpr int LDW1 = 72;   // W1T tile row pitch (64 + 8)
  constexpr int LDW2 = 264;  // W2T chunk row pitch (256 + 8)

  // sA: [128][72] st tile (phase 1 A), then per-wave C->A transpose buffer.
  // sW: phase 1: W1T [256][72]; phase 2: W2T chunk [64][264] (16896 <= 18432 elems).
  __shared__ __align__(16) unsigned short sA[128 * LDA];   // 18432 B
  __shared__ __align__(16) unsigned short sW[256 * LDW1];  // 36864 B   (total 54 KB)

  const int tid  = threadIdx.x;
  const int lane = tid & 63;
  const int wv   = tid >> 6;          // wave 0..3 -> rows [wv*32, wv*32+32)
  const int l15  = lane & 15;
  const int q    = lane >> 4;         // quad 0..3
  const int c    = blockIdx.x & 7;    // expert (== XCD round-robin residue)
  const int row0 = (blockIdx.x >> 3) * 128;

  // ---------------- stage sA (fp32 -> bf16) and sW = W1T[c] ----------------
  {
    const float4* stv = reinterpret_cast<const float4*>(st + (size_t)row0 * S);
    #pragma unroll
    for (int i = 0; i < 8; ++i) {
      int f = tid + i * 256;          // float4 id; 16 per 64-elem row
      int m = f >> 4;
      int qq = f & 15;
      float4 v = stv[f];
      ushort4 p;
      p.x = f2bf(v.x); p.y = f2bf(v.y); p.z = f2bf(v.z); p.w = f2bf(v.w);
      *reinterpret_cast<ushort4*>(sA + m * LDA + qq * 4) = p;
    }
    const uint4* w1v = reinterpret_cast<const uint4*>(W1T + c * HD * S); // 2048 uint4
    #pragma unroll
    for (int i = 0; i < 8; ++i) {
      int f = tid + i * 256;
      int n = f >> 3;                 // 8 uint4 per 64-bf16 row
      int qq = f & 7;
      *reinterpret_cast<uint4*>(sW + n * LDW1 + qq * 8) = w1v[f];
    }
  }
  __syncthreads();

  // h1 A-fragments for phase 2, register resident: [cc(4 k-chunks)][rt(2)][k2(2)]
  bf16x8 aF[4][2][2];

  // ---------------- phase 1: h1 = relu(st @ W1 + b1), M=128 N=256 K=64 ----
  {
    f32x4 acc[2][16];
    #pragma unroll
    for (int rt = 0; rt < 2; ++rt)
      #pragma unroll
      for (int ct = 0; ct < 16; ++ct)
        acc[rt][ct] = (f32x4){0.f, 0.f, 0.f, 0.f};

    #pragma unroll
    for (int ks = 0; ks < 2; ++ks) {
      const int koff = ks * 32 + q * 8;
      bf16x8 a0 = *reinterpret_cast<const bf16x8*>(sA + (wv * 32 + l15) * LDA + koff);
      bf16x8 a1 = *reinterpret_cast<const bf16x8*>(sA + (wv * 32 + 16 + l15) * LDA + koff);
      #pragma unroll
      for (int ct = 0; ct < 16; ++ct) {
        bf16x8 b = *reinterpret_cast<const bf16x8*>(sW + (ct * 16 + l15) * LDW1 + koff);
        acc[0][ct] = __builtin_amdgcn_mfma_f32_16x16x32_bf16(a0, b, acc[0][ct], 0, 0, 0);
        acc[1][ct] = __builtin_amdgcn_mfma_f32_16x16x32_bf16(a1, b, acc[1][ct], 0, 0, 0);
      }
    }

    // epilogue: bias+relu -> bf16; C-layout -> A-layout via this wave's OWN
    // 32 rows of sA (row-split identical in both phases -> wave-private).
    #pragma unroll
    for (int cc = 0; cc < 4; ++cc) {
      #pragma unroll
      for (int rt = 0; rt < 2; ++rt) {
        const int rbase = wv * 32 + rt * 16 + q * 4;
        #pragma unroll
        for (int ctl = 0; ctl < 4; ++ctl) {
          const int ct  = cc * 4 + ctl;
          const int col = ct * 16 + l15;
          const float bias = b1[c * HD + col];
          #pragma unroll
          for (int r = 0; r < 4; ++r) {
            float v = acc[rt][ct][r] + bias;
            v = v > 0.f ? v : 0.f;
            sA[(rbase + r) * LDA + ctl * 16 + l15] = f2bf(v);
          }
        }
      }
      __syncthreads();   // LDS write->read ordering (and uniform across waves)
      #pragma unroll
      for (int rt = 0; rt < 2; ++rt)
        #pragma unroll
        for (int k2 = 0; k2 < 2; ++k2)
          aF[cc][rt][k2] = *reinterpret_cast<const bf16x8*>(
              sA + (wv * 32 + rt * 16 + l15) * LDA + k2 * 32 + q * 8);
      __syncthreads();   // reads done before next chunk overwrites
    }
  }

  // ------- phase 2+3: d = relu(h1 @ W2 + b2) . W3  (h2 never materialized) ----
  float dacc[2][4];
  #pragma unroll
  for (int rt = 0; rt < 2; ++rt)
    #pragma unroll
    for (int r = 0; r < 4; ++r) dacc[rt][r] = 0.f;

  const unsigned short* W2c = W2T + c * HD * HD;
  for (int ch = 0; ch < 4; ++ch) {
    // stage W2T rows n in [ch*64, ch*64+64), full K=256, into sW [64][264]
    // 64 rows x 256 bf16 = 64 x 32 uint4 = 2048 uint4 per chunk
    {
      const uint4* src = reinterpret_cast<const uint4*>(W2c + ch * 64 * HD);
      #pragma unroll
      for (int i = 0; i < 8; ++i) {
        int f = tid + i * 256;
        int n = f >> 5;               // 32 uint4 per 256-bf16 row
        int qq = f & 31;
        *reinterpret_cast<uint4*>(sW + n * LDW2 + qq * 8) = src[f];
      }
    }
    __syncthreads();

    f32x4 acc[2][4];
    #pragma unroll
    for (int rt = 0; rt < 2; ++rt)
      #pragma unroll
      for (int ct = 0; ct < 4; ++ct)
        acc[rt][ct] = (f32x4){0.f, 0.f, 0.f, 0.f};

    #pragma unroll
    for (int ks = 0; ks < 8; ++ks) {
      const int koff = ks * 32 + q * 8;
      const int cc = ks >> 1, k2 = ks & 1;
      #pragma unroll
      for (int ct = 0; ct < 4; ++ct) {
        bf16x8 b = *reinterpret_cast<const bf16x8*>(sW + (ct * 16 + l15) * LDW2 + koff);
        acc[0][ct] = __builtin_amdgcn_mfma_f32_16x16x32_bf16(aF[cc][0][k2], b, acc[0][ct], 0, 0, 0);
        acc[1][ct] = __builtin_amdgcn_mfma_f32_16x16x32_bf16(aF[cc][1][k2], b, acc[1][ct], 0, 0, 0);
      }
    }

    // fused epilogue: relu(h2)*W3 accumulated per row (this lane's 4 cols)
    #pragma unroll
    for (int ct = 0; ct < 4; ++ct) {
      const int n = ch * 64 + ct * 16 + l15;
      const float bias = b2[c * HD + n];
      const float w3v  = W3[c * HD + n];
      #pragma unroll
      for (int rt = 0; rt < 2; ++rt)
        #pragma unroll
        for (int r = 0; r < 4; ++r) {
          float v = acc[rt][ct][r] + bias;
          v = v > 0.f ? v : 0.f;
          dacc[rt][r] += v * w3v;
        }
    }
    __syncthreads();   // sW reads done before next chunk's staging
  }

  // reduce across the 16-lane col groups (cols live in lane&15)
  #pragma unroll
  for (int rt = 0; rt < 2; ++rt)
    #pragma unroll
    for (int r = 0; r < 4; ++r) {
      float v = dacc[rt][r];
      v += __shfl_xor(v, 1);
      v += __shfl_xor(v, 2);
      v += __shfl_xor(v, 4);
      v += __shfl_xor(v, 8);
      dacc[rt][r] = v;
    }

  if (l15 == 0) {
    const float bb = b3[c];
    const int rbase = row0 + wv * 32 + q * 4;
    #pragma unroll
    for (int rt = 0; rt < 2; ++rt)
      #pragma unroll
      for (int r = 0; r < 4; ++r)
        out[(rbase + rt * 16 + r) * C + c] = dacc[rt][r] + bb;
  }
}

extern "C" void kernel_launch(void* const* d_in, const int* in_sizes, int n_in,
                              void* d_out, int out_size, void* d_ws, size_t ws_size,
                              hipStream_t stream)
{
  const float* st = (const float*)d_in[0];
  const float* W1 = (const float*)d_in[1];
  const float* b1 = (const float*)d_in[2];
  const float* W2 = (const float*)d_in[3];
  const float* b2 = (const float*)d_in[4];
  const float* W3 = (const float*)d_in[5];
  const float* b3 = (const float*)d_in[6];
  float* out = (float*)d_out;

  unsigned short* W1T = (unsigned short*)d_ws;         // 131072 bf16
  unsigned short* W2T = W1T + C * HD * S;              // 524288 bf16 (total ~1.3 MB ws)

  prep_weights<<<dim3(2048), dim3(256), 0, stream>>>(W1, W2, W1T, W2T);
  // grid: 512 batch tiles x 8 experts; expert = blockIdx & 7 for XCD L2 locality
  moe_fused<<<dim3(4096), dim3(256), 0, stream>>>(st, W1T, W2T, b1, b2, W3, b3, out);
}